// Round 6
// baseline (233.706 us; speedup 1.0000x reference)
//
#include <hip/hip_runtime.h>
#include <hip/hip_bf16.h>
#include <hip/hip_fp16.h>

// ---------------------------------------------------------------------------
// GCN 2-layer inference:
//   h1 = relu( D^-1/2 (A+I) D^-1/2 (x @ W1) + b1 )
//   out = softmax( D^-1/2 (A+I) D^-1/2 (h1 @ W2) + b2 )
//
// memset(bcur) -> bin (LDS counting-sort by dst-bucket) -> count_b ->
// scan1/2/3 -> fill_b (LDS cursor) -> prepW -> gemm1_mfma (split-bf16 MFMA,
// 8 waves, reg-prefetch, swizzled LDS, *dinv -> fp16) -> agg1 (fp16 gather)
// -> gemm2 -> agg2 (+softmax).
//
// Round-5 lesson: gemm1 was grid/latency-limited (782 blocks x 4 waves =
// 12 waves/CU, occupancy 24%). Now 512-thread blocks (24 waves/CU) +
// register prefetch of next X tile + XOR-swizzled A tile.
// ---------------------------------------------------------------------------

#define F_IN 512
#define NHID 128
#define NCLS 64
#define BSHIFT 8           // 256 nodes per bucket
#define CHUNK 4096         // edges per bin block

typedef __attribute__((ext_vector_type(8))) short short8;
typedef __attribute__((ext_vector_type(4))) short short4v;
typedef __attribute__((ext_vector_type(4))) float f32x4;

__device__ __forceinline__ unsigned f2u(float f) { union { float f; unsigned u; } v; v.f = f; return v.u; }
__device__ __forceinline__ float u2f(unsigned u) { union { unsigned u; float f; } v; v.u = u; return v.f; }

// ---------------- binning: LDS counting-sort of 4096-edge chunks by bucket ----------------

__global__ __launch_bounds__(256) void bin_kernel(const int* __restrict__ src,
        const int* __restrict__ dst, int2* __restrict__ pairs,
        int* __restrict__ bcur, int E, int cap) {
    __shared__ int lcnt[256];
    __shared__ int lscan[256];
    __shared__ int gbase[256];
    __shared__ int wsum[4];
    __shared__ int2 stage[CHUNK];
    const int t = threadIdx.x;
    const int lane = t & 63, wid = t >> 6;
    const int e0 = blockIdx.x * CHUNK;
    const int n = min(CHUNK, E - e0);

    lcnt[t] = 0;
    __syncthreads();
    for (int i = t; i < n; i += 256)
        atomicAdd(&lcnt[dst[e0 + i] >> BSHIFT], 1);
    __syncthreads();
    const int v = lcnt[t];
    int s = v;
    #pragma unroll
    for (int d = 1; d < 64; d <<= 1) {
        int tt = __shfl_up(s, d);
        if (lane >= d) s += tt;
    }
    if (lane == 63) wsum[wid] = s;
    __syncthreads();
    int woff = 0;
    for (int w = 0; w < wid; ++w) woff += wsum[w];
    lscan[t] = woff + s - v;
    gbase[t] = v ? atomicAdd(&bcur[t], v) : 0;
    lcnt[t] = 0;
    __syncthreads();
    for (int i = t; i < n; i += 256) {
        int d = dst[e0 + i], sc = src[e0 + i];
        int b = d >> BSHIFT;
        int p = atomicAdd(&lcnt[b], 1);
        stage[lscan[b] + p] = make_int2(d, sc);
    }
    __syncthreads();
    // dense run writes: consecutive i within a run -> consecutive addresses
    for (int i = t; i < n; i += 256) {
        int2 pr = stage[i];
        int b = pr.x >> BSHIFT;
        int off = gbase[b] + (i - lscan[b]);
        if (off < cap) pairs[(size_t)b * cap + off] = pr;
    }
}

// ---------------- per-bucket degree count (LDS histogram, dense cnt write) ----------------

__global__ __launch_bounds__(256) void count_b_kernel(const int2* __restrict__ pairs,
        const int* __restrict__ bcur, int* __restrict__ cnt, int cap) {
    __shared__ int hist[256];
    const int b = blockIdx.x;
    const int t = threadIdx.x;
    hist[t] = 0;
    __syncthreads();
    const int n = min(bcur[b], cap);
    const int2* p = pairs + (size_t)b * cap;
    for (int i = t; i < n; i += 256)
        atomicAdd(&hist[p[i].x & 255], 1);
    __syncthreads();
    cnt[(b << BSHIFT) + t] = hist[t];
}

// ---------------- row_ptr scan ----------------

__global__ __launch_bounds__(256) void scan1_kernel(const int* __restrict__ cnt,
        int* __restrict__ row_ptr, float* __restrict__ dinv,
        int* __restrict__ bsum, int N) {
    __shared__ int wsum[4];
    const int tid = threadIdx.x;
    const int lane = tid & 63, wid = tid >> 6;
    const int base = blockIdx.x * 1024 + tid * 4;
    int4 v = {0, 0, 0, 0};
    if (base + 3 < N) {
        v = *reinterpret_cast<const int4*>(&cnt[base]);
    } else {
        if (base + 0 < N) v.x = cnt[base + 0];
        if (base + 1 < N) v.y = cnt[base + 1];
        if (base + 2 < N) v.z = cnt[base + 2];
        if (base + 3 < N) v.w = cnt[base + 3];
    }
    if (base + 0 < N) dinv[base + 0] = rsqrtf((float)v.x + 1.0f);
    if (base + 1 < N) dinv[base + 1] = rsqrtf((float)v.y + 1.0f);
    if (base + 2 < N) dinv[base + 2] = rsqrtf((float)v.z + 1.0f);
    if (base + 3 < N) dinv[base + 3] = rsqrtf((float)v.w + 1.0f);
    const int tsum = v.x + v.y + v.z + v.w;
    int s = tsum;
    #pragma unroll
    for (int d = 1; d < 64; d <<= 1) {
        int t = __shfl_up(s, d);
        if (lane >= d) s += t;
    }
    if (lane == 63) wsum[wid] = s;
    __syncthreads();
    int woff = 0;
    for (int w = 0; w < wid; ++w) woff += wsum[w];
    const int excl = woff + s - tsum;
    if (base + 0 < N) row_ptr[base + 0] = excl;
    if (base + 1 < N) row_ptr[base + 1] = excl + v.x;
    if (base + 2 < N) row_ptr[base + 2] = excl + v.x + v.y;
    if (base + 3 < N) row_ptr[base + 3] = excl + v.x + v.y + v.z;
    if (tid == 255) bsum[blockIdx.x] = excl + tsum;
}

__global__ __launch_bounds__(64) void scan2_kernel(const int* __restrict__ bsum,
        int* __restrict__ boff, int* __restrict__ row_ptr, int nb, int N) {
    const int lane = threadIdx.x;
    int v = (lane < nb) ? bsum[lane] : 0;
    int s = v;
    #pragma unroll
    for (int d = 1; d < 64; d <<= 1) {
        int t = __shfl_up(s, d);
        if (lane >= d) s += t;
    }
    if (lane < nb) boff[lane] = s - v;
    if (lane == 63) row_ptr[N] = s;
}

__global__ void scan3_kernel(int* __restrict__ row_ptr, const int* __restrict__ boff, int N) {
    int i = blockIdx.x * blockDim.x + threadIdx.x;
    if (i < N) row_ptr[i] += boff[i >> 10];
}

// ---------------- CSR placement: LDS cursor, bucket-local col writes ----------------

__global__ __launch_bounds__(512) void fill_b_kernel(const int2* __restrict__ pairs,
        const int* __restrict__ bcur, const int* __restrict__ row_ptr,
        int* __restrict__ col, int cap) {
    __shared__ int lcur[256];
    const int b = blockIdx.x;
    const int t = threadIdx.x;
    if (t < 256) lcur[t] = 0;
    __syncthreads();
    const int n = min(bcur[b], cap);
    const int2* p = pairs + (size_t)b * cap;
    for (int i = t; i < n; i += 512) {
        int2 pr = p[i];
        int pos = row_ptr[pr.x] + atomicAdd(&lcur[pr.x & 255], 1);
        col[pos] = pr.y;
    }
}

// ---------------- prepW: W1 [512][128] f32 -> WhiT/WloT [128][512] bf16 ----------------

__global__ __launch_bounds__(256) void prepW_kernel(const float* __restrict__ W1,
        short* __restrict__ WhiT, short* __restrict__ WloT) {
    int idx = blockIdx.x * 256 + threadIdx.x;
    int k = idx >> 7;
    int n = idx & 127;
    float w = W1[idx];
    unsigned u = f2u(w);
    short h = (short)(u >> 16);
    float hif = u2f(u & 0xffff0000u);
    short l = (short)(f2u(w - hif) >> 16);
    WhiT[(size_t)n * F_IN + k] = h;
    WloT[(size_t)n * F_IN + k] = l;
}

// ---------------- GEMM1: Hs16 = fp16((x @ W1) * dinv[row]) via split-bf16 MFMA ----------------
// 512 threads = 8 waves: wave w -> rows (w>>2)*32..+32, cols (w&3)*32..+32.
// A tile [64][32] shorts, XOR-swizzled: byte ^= (row&7)<<4 -> b128 read starts
// spread over all 8 16B slots. Register prefetch of next X float4 hides HBM
// latency across the iteration; B loads issued before barriers (L2-hot).

__global__ __launch_bounds__(512, 6) void gemm1_mfma(
        const float* __restrict__ X, const short* __restrict__ WhiT,
        const short* __restrict__ WloT, const float* __restrict__ dinv,
        __half* __restrict__ Hs16, int M) {
    __shared__ short Ahi[64 * 32];
    __shared__ short Alo[64 * 32];
    const int tid = threadIdx.x;
    const int lane = tid & 63;
    const int wid = tid >> 6;          // 0..7
    const int m0 = blockIdx.x * 64;
    const int rh = wid >> 2;           // row half (32 rows)
    const int n0 = (wid & 3) * 32;     // col group
    const int l15 = lane & 15;
    const int kc = lane >> 4;

    // staging: thread t -> row t>>3 (0..63), float4 slot t&7
    const int sr = tid >> 3;
    const int sc = tid & 7;
    int grow = m0 + sr; if (grow > M - 1) grow = M - 1;
    const float* xp = X + (size_t)grow * F_IN + sc * 4;
    const int wb = (sr * 64 + sc * 8) ^ ((sr & 7) << 4);
    char* ahw = (char*)Ahi + wb;
    char* alw = (char*)Alo + wb;

    const short* bhp = WhiT + (size_t)(n0 + l15) * F_IN + kc * 8;
    const short* blp = WloT + (size_t)(n0 + l15) * F_IN + kc * 8;

    const int r0 = rh * 32 + l15;      // mt=0 row
    const int r1 = r0 + 16;            // mt=1 row
    const int ra0 = (r0 * 64 + kc * 16) ^ ((r0 & 7) << 4);
    const int ra1 = (r1 * 64 + kc * 16) ^ ((r1 & 7) << 4);

    f32x4 acc[2][2];
    #pragma unroll
    for (int i = 0; i < 2; ++i)
        #pragma unroll
        for (int j = 0; j < 2; ++j)
            acc[i][j] = (f32x4){0.f, 0.f, 0.f, 0.f};

    float4 a_nxt = *reinterpret_cast<const float4*>(xp);
    for (int k0 = 0; k0 < F_IN; k0 += 32) {
        float4 a = a_nxt;
        const float* pn = xp + (k0 + 32 < F_IN ? k0 + 32 : 0);
        a_nxt = *reinterpret_cast<const float4*>(pn);     // prefetch next tile
        short8 bh0 = *reinterpret_cast<const short8*>(bhp + k0);
        short8 bl0 = *reinterpret_cast<const short8*>(blp + k0);
        short8 bh1 = *reinterpret_cast<const short8*>(bhp + 16 * F_IN + k0);
        short8 bl1 = *reinterpret_cast<const short8*>(blp + 16 * F_IN + k0);
        float av[4] = {a.x, a.y, a.z, a.w};
        short4v vh, vl;
        #pragma unroll
        for (int j = 0; j < 4; ++j) {
            unsigned u = f2u(av[j]);
            vh[j] = (short)(u >> 16);
            float hif = u2f(u & 0xffff0000u);
            vl[j] = (short)(f2u(av[j] - hif) >> 16);
        }
        __syncthreads();   // previous iteration's readers done
        *reinterpret_cast<short4v*>(ahw) = vh;
        *reinterpret_cast<short4v*>(alw) = vl;
        __syncthreads();   // tile visible
        const short8 ah0 = *reinterpret_cast<const short8*>((char*)Ahi + ra0);
        const short8 al0 = *reinterpret_cast<const short8*>((char*)Alo + ra0);
        const short8 ah1 = *reinterpret_cast<const short8*>((char*)Ahi + ra1);
        const short8 al1 = *reinterpret_cast<const short8*>((char*)Alo + ra1);
        acc[0][0] = __builtin_amdgcn_mfma_f32_16x16x32_bf16(ah0, bh0, acc[0][0], 0, 0, 0);
        acc[0][0] = __builtin_amdgcn_mfma_f32_16x16x32_bf16(ah0, bl0, acc[0][0], 0, 0, 0);
        acc[0][0] = __builtin_amdgcn_mfma_f32_16x16x32_bf16(al0, bh0, acc[0][0], 0, 0, 0);
        acc[0][1] = __builtin_amdgcn_mfma_f32_16x16x32_bf16(ah0, bh1, acc[0][1], 0, 0, 0);
        acc[0][1] = __builtin_amdgcn_mfma_f32_16x16x32_bf16(ah0, bl1, acc[0][1], 0, 0, 0);
        acc[0][1] = __builtin_amdgcn_mfma_f32_16x16x32_bf16(al0, bh1, acc[0][1], 0, 0, 0);
        acc[1][0] = __builtin_amdgcn_mfma_f32_16x16x32_bf16(ah1, bh0, acc[1][0], 0, 0, 0);
        acc[1][0] = __builtin_amdgcn_mfma_f32_16x16x32_bf16(ah1, bl0, acc[1][0], 0, 0, 0);
        acc[1][0] = __builtin_amdgcn_mfma_f32_16x16x32_bf16(al1, bh0, acc[1][0], 0, 0, 0);
        acc[1][1] = __builtin_amdgcn_mfma_f32_16x16x32_bf16(ah1, bh1, acc[1][1], 0, 0, 0);
        acc[1][1] = __builtin_amdgcn_mfma_f32_16x16x32_bf16(ah1, bl1, acc[1][1], 0, 0, 0);
        acc[1][1] = __builtin_amdgcn_mfma_f32_16x16x32_bf16(al1, bh1, acc[1][1], 0, 0, 0);
    }
    #pragma unroll
    for (int mt = 0; mt < 2; ++mt) {
        #pragma unroll
        for (int r = 0; r < 4; ++r) {
            int row = m0 + rh * 32 + mt * 16 + kc * 4 + r;
            if (row < M) {
                float di = dinv[row];
                #pragma unroll
                for (int nt = 0; nt < 2; ++nt) {
                    Hs16[(size_t)row * NHID + n0 + nt * 16 + l15] =
                        __float2half(acc[mt][nt][r] * di);
                }
            }
        }
    }
}

// ---------------- AGG1: Y = relu(dinv[i]*(Hs[i] + sum Hs[src]) + b1) ----------------

__global__ __launch_bounds__(64) void agg1_kernel(const __half2* __restrict__ Hs,
        const int* __restrict__ row_ptr, const int* __restrict__ col,
        const float* __restrict__ dinv, const float* __restrict__ b1,
        float* __restrict__ Y) {
    const int i = blockIdx.x;
    const int c = threadIdx.x;           // col-pair 0..63
    const int beg = row_ptr[i], end = row_ptr[i + 1];
    float2 f = __half22float2(Hs[(size_t)i * 64 + c]);
    float ax = f.x, ay = f.y;
    int e = beg;
    for (; e + 8 <= end; e += 8) {
        float2 v[8];
        #pragma unroll
        for (int j = 0; j < 8; ++j) {
            int s = col[e + j];
            v[j] = __half22float2(Hs[(size_t)s * 64 + c]);
        }
        #pragma unroll
        for (int j = 0; j < 8; ++j) { ax += v[j].x; ay += v[j].y; }
    }
    for (; e < end; ++e) {
        float2 v = __half22float2(Hs[(size_t)col[e] * 64 + c]);
        ax += v.x; ay += v.y;
    }
    const float di = dinv[i];
    const float2 bb = reinterpret_cast<const float2*>(b1)[c];
    float2 o;
    o.x = fmaxf(fmaf(ax, di, bb.x), 0.0f);
    o.y = fmaxf(fmaf(ay, di, bb.y), 0.0f);
    *reinterpret_cast<float2*>(&Y[(size_t)i * NHID + 2 * c]) = o;
}

// ---------------- GEMM2: H2s16 = fp16((Y @ W2) * dinv[row])  [N,64] ----------------

__global__ __launch_bounds__(256) void gemm2_kernel(const float* __restrict__ Y,
        const float* __restrict__ W2, const float* __restrict__ dinv,
        __half* __restrict__ H2s16, int N) {
    __shared__ float Ws[NHID][NCLS];
    __shared__ float Ys[16][NHID];
    const int tid = threadIdx.x;
    const int i0 = blockIdx.x * 16;
    #pragma unroll
    for (int t = 0; t < 8; ++t) {
        int v = tid + t * 256;
        int k = v >> 4;
        int c4 = (v & 15) * 4;
        *reinterpret_cast<float4*>(&Ws[k][c4]) =
            *reinterpret_cast<const float4*>(&W2[(size_t)k * NCLS + c4]);
    }
    #pragma unroll
    for (int t = 0; t < 2; ++t) {
        int v = tid + t * 256;
        int r = v >> 5;
        int c4 = (v & 31) * 4;
        int gr = i0 + r; if (gr > N - 1) gr = N - 1;
        *reinterpret_cast<float4*>(&Ys[r][c4]) =
            *reinterpret_cast<const float4*>(&Y[(size_t)gr * NHID + c4]);
    }
    __syncthreads();
    const int c = tid & 63;
    const int rg = tid >> 6;
    float acc[4] = {0.f, 0.f, 0.f, 0.f};
    #pragma unroll 8
    for (int k = 0; k < NHID; ++k) {
        float w = Ws[k][c];
        #pragma unroll
        for (int j = 0; j < 4; ++j)
            acc[j] = fmaf(Ys[rg * 4 + j][k], w, acc[j]);
    }
    #pragma unroll
    for (int j = 0; j < 4; ++j) {
        int gr = i0 + rg * 4 + j;
        if (gr < N) H2s16[(size_t)gr * NCLS + c] = __float2half(acc[j] * dinv[gr]);
    }
}

// ---------------- AGG2 + softmax: two nodes per wave ----------------

__global__ __launch_bounds__(64) void agg2_kernel(const __half2* __restrict__ H2,
        const int* __restrict__ row_ptr, const int* __restrict__ col,
        const float* __restrict__ dinv, const float* __restrict__ b2,
        float* __restrict__ out, int N) {
    const int lane = threadIdx.x;
    const int node = blockIdx.x * 2 + (lane >> 5);
    const int c = lane & 31;             // col-pair 0..31
    if (node >= N) return;
    const int beg = row_ptr[node], end = row_ptr[node + 1];
    float2 f = __half22float2(H2[(size_t)node * 32 + c]);
    float ax = f.x, ay = f.y;
    int e = beg;
    for (; e + 8 <= end; e += 8) {
        float2 v[8];
        #pragma unroll
        for (int j = 0; j < 8; ++j) {
            int s = col[e + j];
            v[j] = __half22float2(H2[(size_t)s * 32 + c]);
        }
        #pragma unroll
        for (int j = 0; j < 8; ++j) { ax += v[j].x; ay += v[j].y; }
    }
    for (; e < end; ++e) {
        float2 v = __half22float2(H2[(size_t)col[e] * 32 + c]);
        ax += v.x; ay += v.y;
    }
    const float di = dinv[node];
    const float2 bb = reinterpret_cast<const float2*>(b2)[c];
    float vx = fmaf(ax, di, bb.x);
    float vy = fmaf(ay, di, bb.y);
    float m = fmaxf(vx, vy);
    #pragma unroll
    for (int d = 16; d >= 1; d >>= 1) m = fmaxf(m, __shfl_xor(m, d));
    float ex = __expf(vx - m), ey = __expf(vy - m);
    float sum = ex + ey;
    #pragma unroll
    for (int d = 16; d >= 1; d >>= 1) sum += __shfl_xor(sum, d);
    float2 o = {ex / sum, ey / sum};
    reinterpret_cast<float2*>(out)[(size_t)node * 32 + c] = o;
}

// ---------------- launch ----------------

extern "C" void kernel_launch(void* const* d_in, const int* in_sizes, int n_in,
                              void* d_out, int out_size, void* d_ws, size_t ws_size,
                              hipStream_t stream) {
    const float* x  = (const float*)d_in[0];
    const int*   ei = (const int*)d_in[1];
    const float* W1 = (const float*)d_in[2];
    const float* b1 = (const float*)d_in[3];
    const float* W2 = (const float*)d_in[4];
    const float* b2 = (const float*)d_in[5];
    const int N = in_sizes[0] / F_IN;
    const int E = in_sizes[1] / 2;
    const int* src = ei;
    const int* dst = ei + E;
    float* out = (float*)d_out;

    const int Npad  = (N + 63) & ~63;
    const int Nb256 = (N + 255) & ~255;           // cnt size (bucket-dense)
    const int Epad  = (E + 63) & ~63;
    int*    cnt     = (int*)d_ws;                 // Nb256
    int*    bcur    = cnt + Nb256;                // 256
    int*    row_ptr = bcur + 256;                 // Npad (>= N+1)
    float*  dinv    = (float*)(row_ptr + Npad);   // Npad
    int*    col     = (int*)(dinv + Npad);        // Epad
    int*    bsum    = col + Epad;                 // 64
    int*    boff    = bsum + 64;                  // 64
    __half* Hs16    = (__half*)(boff + 64);       // Npad*128 halfs (12.8MB)
    float*  Y       = (float*)(Hs16 + (size_t)Npad * NHID);  // Npad*128 f32 (25.6MB)
    __half* H2s16   = Hs16;                       // reuse (Hs dead after agg1)
    short*  WhiT    = (short*)Y;                  // overlay Y start (256KB)
    short*  WloT    = WhiT + (size_t)F_IN * NHID;
    // bucket pair storage overlays Y at +512KB; dead before agg1 writes Y
    int2*   pairs   = (int2*)((char*)Y + 512 * 1024);

    const int nb = (N + 1023) / 1024;
    const int nbuck = (N + 255) >> BSHIFT;                  // 196
    const int cap = (((E / nbuck) * 3 / 2) + 63) & ~63;     // ~12288

    hipMemsetAsync(bcur, 0, 256 * sizeof(int), stream);
    bin_kernel<<<(E + CHUNK - 1) / CHUNK, 256, 0, stream>>>(src, dst, pairs, bcur, E, cap);
    count_b_kernel<<<nbuck, 256, 0, stream>>>(pairs, bcur, cnt, cap);
    scan1_kernel<<<nb, 256, 0, stream>>>(cnt, row_ptr, dinv, bsum, N);
    scan2_kernel<<<1, 64, 0, stream>>>(bsum, boff, row_ptr, nb, N);
    scan3_kernel<<<(N + 255) / 256, 256, 0, stream>>>(row_ptr, boff, N);
    fill_b_kernel<<<nbuck, 512, 0, stream>>>(pairs, bcur, row_ptr, col, cap);
    prepW_kernel<<<(F_IN * NHID) / 256, 256, 0, stream>>>(W1, WhiT, WloT);
    gemm1_mfma<<<(N + 63) / 64, 512, 0, stream>>>(x, WhiT, WloT, dinv, Hs16, N);
    agg1_kernel<<<N, 64, 0, stream>>>((const __half2*)Hs16, row_ptr, col, dinv, b1, Y);
    gemm2_kernel<<<(N + 15) / 16, 256, 0, stream>>>(Y, W2, dinv, H2s16, N);
    agg2_kernel<<<(N + 1) / 2, 64, 0, stream>>>((const __half2*)H2s16, row_ptr, col, dinv, b2, out, N);
}

// Round 7
// 221.633 us; speedup vs baseline: 1.0545x; 1.0545x over previous
//
#include <hip/hip_runtime.h>
#include <hip/hip_bf16.h>
#include <hip/hip_fp16.h>

// ---------------------------------------------------------------------------
// GCN 2-layer inference:
//   h1 = relu( D^-1/2 (A+I) D^-1/2 (x @ W1) + b1 )
//   out = softmax( D^-1/2 (A+I) D^-1/2 (h1 @ W2) + b2 )
//
// memset(bcur) -> bin (LDS counting-sort by dst-bucket) -> count_b ->
// scan1/2/3 -> fill_b (LDS cursor) -> prepW (fragment-packed hi/lo bf16) ->
// gemm1_mfma (REGISTER-DIRECT split-bf16 MFMA: no LDS, no barriers) ->
// agg1 (fp16 gather) -> gemm2 -> agg2 (+softmax).
//
// Round-6 lesson: barrier-coupled MFMA staging was the limiter, not
// occupancy (8-wave + 2 barriers/K-step REGRESSED 64->95us at 42% occ).
// A-fragment rows are lane-local for 16x16x32 => load X straight to
// registers (100% coalesced: 4 lanes x 32B = 128B/row), convert in-reg,
// MFMA. B comes from fragment-packed W (1KB contiguous per wave-load).
// ---------------------------------------------------------------------------

#define F_IN 512
#define NHID 128
#define NCLS 64
#define BSHIFT 8           // 256 nodes per bucket
#define CHUNK 4096         // edges per bin block

typedef __attribute__((ext_vector_type(8))) short short8;
typedef __attribute__((ext_vector_type(4))) float f32x4;

__device__ __forceinline__ unsigned f2u(float f) { union { float f; unsigned u; } v; v.f = f; return v.u; }
__device__ __forceinline__ float u2f(unsigned u) { union { unsigned u; float f; } v; v.u = u; return v.f; }

// ---------------- binning: LDS counting-sort of 4096-edge chunks by bucket ----------------

__global__ __launch_bounds__(256) void bin_kernel(const int* __restrict__ src,
        const int* __restrict__ dst, int2* __restrict__ pairs,
        int* __restrict__ bcur, int E, int cap) {
    __shared__ int lcnt[256];
    __shared__ int lscan[256];
    __shared__ int gbase[256];
    __shared__ int wsum[4];
    __shared__ int2 stage[CHUNK];
    const int t = threadIdx.x;
    const int lane = t & 63, wid = t >> 6;
    const int e0 = blockIdx.x * CHUNK;
    const int n = min(CHUNK, E - e0);

    lcnt[t] = 0;
    __syncthreads();
    for (int i = t; i < n; i += 256)
        atomicAdd(&lcnt[dst[e0 + i] >> BSHIFT], 1);
    __syncthreads();
    const int v = lcnt[t];
    int s = v;
    #pragma unroll
    for (int d = 1; d < 64; d <<= 1) {
        int tt = __shfl_up(s, d);
        if (lane >= d) s += tt;
    }
    if (lane == 63) wsum[wid] = s;
    __syncthreads();
    int woff = 0;
    for (int w = 0; w < wid; ++w) woff += wsum[w];
    lscan[t] = woff + s - v;
    gbase[t] = v ? atomicAdd(&bcur[t], v) : 0;
    lcnt[t] = 0;
    __syncthreads();
    for (int i = t; i < n; i += 256) {
        int d = dst[e0 + i], sc = src[e0 + i];
        int b = d >> BSHIFT;
        int p = atomicAdd(&lcnt[b], 1);
        stage[lscan[b] + p] = make_int2(d, sc);
    }
    __syncthreads();
    for (int i = t; i < n; i += 256) {
        int2 pr = stage[i];
        int b = pr.x >> BSHIFT;
        int off = gbase[b] + (i - lscan[b]);
        if (off < cap) pairs[(size_t)b * cap + off] = pr;
    }
}

// ---------------- per-bucket degree count (LDS histogram, dense cnt write) ----------------

__global__ __launch_bounds__(256) void count_b_kernel(const int2* __restrict__ pairs,
        const int* __restrict__ bcur, int* __restrict__ cnt, int cap) {
    __shared__ int hist[256];
    const int b = blockIdx.x;
    const int t = threadIdx.x;
    hist[t] = 0;
    __syncthreads();
    const int n = min(bcur[b], cap);
    const int2* p = pairs + (size_t)b * cap;
    for (int i = t; i < n; i += 256)
        atomicAdd(&hist[p[i].x & 255], 1);
    __syncthreads();
    cnt[(b << BSHIFT) + t] = hist[t];
}

// ---------------- row_ptr scan ----------------

__global__ __launch_bounds__(256) void scan1_kernel(const int* __restrict__ cnt,
        int* __restrict__ row_ptr, float* __restrict__ dinv,
        int* __restrict__ bsum, int N) {
    __shared__ int wsum[4];
    const int tid = threadIdx.x;
    const int lane = tid & 63, wid = tid >> 6;
    const int base = blockIdx.x * 1024 + tid * 4;
    int4 v = {0, 0, 0, 0};
    if (base + 3 < N) {
        v = *reinterpret_cast<const int4*>(&cnt[base]);
    } else {
        if (base + 0 < N) v.x = cnt[base + 0];
        if (base + 1 < N) v.y = cnt[base + 1];
        if (base + 2 < N) v.z = cnt[base + 2];
        if (base + 3 < N) v.w = cnt[base + 3];
    }
    if (base + 0 < N) dinv[base + 0] = rsqrtf((float)v.x + 1.0f);
    if (base + 1 < N) dinv[base + 1] = rsqrtf((float)v.y + 1.0f);
    if (base + 2 < N) dinv[base + 2] = rsqrtf((float)v.z + 1.0f);
    if (base + 3 < N) dinv[base + 3] = rsqrtf((float)v.w + 1.0f);
    const int tsum = v.x + v.y + v.z + v.w;
    int s = tsum;
    #pragma unroll
    for (int d = 1; d < 64; d <<= 1) {
        int t = __shfl_up(s, d);
        if (lane >= d) s += t;
    }
    if (lane == 63) wsum[wid] = s;
    __syncthreads();
    int woff = 0;
    for (int w = 0; w < wid; ++w) woff += wsum[w];
    const int excl = woff + s - tsum;
    if (base + 0 < N) row_ptr[base + 0] = excl;
    if (base + 1 < N) row_ptr[base + 1] = excl + v.x;
    if (base + 2 < N) row_ptr[base + 2] = excl + v.x + v.y;
    if (base + 3 < N) row_ptr[base + 3] = excl + v.x + v.y + v.z;
    if (tid == 255) bsum[blockIdx.x] = excl + tsum;
}

__global__ __launch_bounds__(64) void scan2_kernel(const int* __restrict__ bsum,
        int* __restrict__ boff, int* __restrict__ row_ptr, int nb, int N) {
    const int lane = threadIdx.x;
    int v = (lane < nb) ? bsum[lane] : 0;
    int s = v;
    #pragma unroll
    for (int d = 1; d < 64; d <<= 1) {
        int t = __shfl_up(s, d);
        if (lane >= d) s += t;
    }
    if (lane < nb) boff[lane] = s - v;
    if (lane == 63) row_ptr[N] = s;
}

__global__ void scan3_kernel(int* __restrict__ row_ptr, const int* __restrict__ boff, int N) {
    int i = blockIdx.x * blockDim.x + threadIdx.x;
    if (i < N) row_ptr[i] += boff[i >> 10];
}

// ---------------- CSR placement: LDS cursor, bucket-local col writes ----------------

__global__ __launch_bounds__(512) void fill_b_kernel(const int2* __restrict__ pairs,
        const int* __restrict__ bcur, const int* __restrict__ row_ptr,
        int* __restrict__ col, int cap) {
    __shared__ int lcur[256];
    const int b = blockIdx.x;
    const int t = threadIdx.x;
    if (t < 256) lcur[t] = 0;
    __syncthreads();
    const int n = min(bcur[b], cap);
    const int2* p = pairs + (size_t)b * cap;
    for (int i = t; i < n; i += 512) {
        int2 pr = p[i];
        int pos = row_ptr[pr.x] + atomicAdd(&lcur[pr.x & 255], 1);
        col[pos] = pr.y;
    }
}

// ---------------- prepW: W1 -> fragment-packed hi/lo bf16 ----------------
// Fragment f = ks*8 + nt (ks: K-step of 32, nt: 16-col tile). Lane l of
// frag f needs cols nt*16+(l&15), k = ks*32+(l>>4)*8 .. +8. Packed at
// [f*512 + l*8] shorts => gemm1's B-frag load is 1KB contiguous per wave.

__global__ __launch_bounds__(256) void prepW_kernel(const float* __restrict__ W1,
        short* __restrict__ Whp, short* __restrict__ Wlp) {
    const int g = blockIdx.x * 256 + threadIdx.x;  // 0..8191
    const int f = g >> 6;
    const int lane = g & 63;
    const int ks = f >> 3, nt = f & 7;
    const int colg = nt * 16 + (lane & 15);
    const int k0 = ks * 32 + (lane >> 4) * 8;
    short8 vh, vl;
    #pragma unroll
    for (int j = 0; j < 8; ++j) {
        float w = W1[(size_t)(k0 + j) * NHID + colg];
        unsigned u = f2u(w);
        vh[j] = (short)(u >> 16);
        float hif = u2f(u & 0xffff0000u);
        vl[j] = (short)(f2u(w - hif) >> 16);
    }
    *reinterpret_cast<short8*>(Whp + ((size_t)f << 9) + (lane << 3)) = vh;
    *reinterpret_cast<short8*>(Wlp + ((size_t)f << 9) + (lane << 3)) = vl;
}

// ---------------- GEMM1: register-direct split-bf16 MFMA, no LDS/barriers ----------------
// 256 threads = 4 waves; wave w owns rows blockIdx.x*64 + w*16 .. +16, all
// 128 cols (8 ntiles). A: lane loads its own X[row=l&15][kc*8..+8] (32B,
// coalesces to 128B/row), converts to hi/lo bf16 in registers. B: packed
// frags, 1KB contiguous per wave-load, L1/L2-hot. 24 MFMA per K-step.

__global__ __launch_bounds__(256, 4) void gemm1_mfma(
        const float* __restrict__ X, const short* __restrict__ Whp,
        const short* __restrict__ Wlp, const float* __restrict__ dinv,
        __half* __restrict__ Hs16, int M) {
    const int tid = threadIdx.x;
    const int lane = tid & 63;
    const int wid = tid >> 6;
    const int l15 = lane & 15;
    const int kc = lane >> 4;
    const int rbase = blockIdx.x * 64 + wid * 16;

    int arow = rbase + l15; if (arow > M - 1) arow = M - 1;
    const float* xp = X + (size_t)arow * F_IN + kc * 8;
    const short* whp = Whp + (lane << 3);
    const short* wlp = Wlp + (lane << 3);

    f32x4 acc[8];
    #pragma unroll
    for (int nt = 0; nt < 8; ++nt) acc[nt] = (f32x4){0.f, 0.f, 0.f, 0.f};

    #pragma unroll 4
    for (int ks = 0; ks < 16; ++ks) {
        float4 a0 = *reinterpret_cast<const float4*>(xp + ks * 32);
        float4 a1 = *reinterpret_cast<const float4*>(xp + ks * 32 + 4);
        float av[8] = {a0.x, a0.y, a0.z, a0.w, a1.x, a1.y, a1.z, a1.w};
        short8 ah, al;
        #pragma unroll
        for (int j = 0; j < 8; ++j) {
            unsigned u = f2u(av[j]);
            ah[j] = (short)(u >> 16);
            float hif = u2f(u & 0xffff0000u);
            al[j] = (short)(f2u(av[j] - hif) >> 16);
        }
        #pragma unroll
        for (int nt = 0; nt < 8; ++nt) {
            const size_t fo = (size_t)(ks * 8 + nt) << 9;
            short8 bh = *reinterpret_cast<const short8*>(whp + fo);
            short8 bl = *reinterpret_cast<const short8*>(wlp + fo);
            acc[nt] = __builtin_amdgcn_mfma_f32_16x16x32_bf16(ah, bh, acc[nt], 0, 0, 0);
            acc[nt] = __builtin_amdgcn_mfma_f32_16x16x32_bf16(ah, bl, acc[nt], 0, 0, 0);
            acc[nt] = __builtin_amdgcn_mfma_f32_16x16x32_bf16(al, bh, acc[nt], 0, 0, 0);
        }
    }
    #pragma unroll
    for (int r = 0; r < 4; ++r) {
        const int orow = rbase + kc * 4 + r;
        if (orow < M) {
            const float di = dinv[orow];
            #pragma unroll
            for (int nt = 0; nt < 8; ++nt) {
                Hs16[(size_t)orow * NHID + nt * 16 + l15] =
                    __float2half(acc[nt][r] * di);
            }
        }
    }
}

// ---------------- AGG1: Y = relu(dinv[i]*(Hs[i] + sum Hs[src]) + b1) ----------------

__global__ __launch_bounds__(64) void agg1_kernel(const __half2* __restrict__ Hs,
        const int* __restrict__ row_ptr, const int* __restrict__ col,
        const float* __restrict__ dinv, const float* __restrict__ b1,
        float* __restrict__ Y) {
    const int i = blockIdx.x;
    const int c = threadIdx.x;           // col-pair 0..63
    const int beg = row_ptr[i], end = row_ptr[i + 1];
    float2 f = __half22float2(Hs[(size_t)i * 64 + c]);
    float ax = f.x, ay = f.y;
    int e = beg;
    for (; e + 8 <= end; e += 8) {
        float2 v[8];
        #pragma unroll
        for (int j = 0; j < 8; ++j) {
            int s = col[e + j];
            v[j] = __half22float2(Hs[(size_t)s * 64 + c]);
        }
        #pragma unroll
        for (int j = 0; j < 8; ++j) { ax += v[j].x; ay += v[j].y; }
    }
    for (; e < end; ++e) {
        float2 v = __half22float2(Hs[(size_t)col[e] * 64 + c]);
        ax += v.x; ay += v.y;
    }
    const float di = dinv[i];
    const float2 bb = reinterpret_cast<const float2*>(b1)[c];
    float2 o;
    o.x = fmaxf(fmaf(ax, di, bb.x), 0.0f);
    o.y = fmaxf(fmaf(ay, di, bb.y), 0.0f);
    *reinterpret_cast<float2*>(&Y[(size_t)i * NHID + 2 * c]) = o;
}

// ---------------- GEMM2: H2s16 = fp16((Y @ W2) * dinv[row])  [N,64] ----------------

__global__ __launch_bounds__(256) void gemm2_kernel(const float* __restrict__ Y,
        const float* __restrict__ W2, const float* __restrict__ dinv,
        __half* __restrict__ H2s16, int N) {
    __shared__ float Ws[NHID][NCLS];
    __shared__ float Ys[16][NHID];
    const int tid = threadIdx.x;
    const int i0 = blockIdx.x * 16;
    #pragma unroll
    for (int t = 0; t < 8; ++t) {
        int v = tid + t * 256;
        int k = v >> 4;
        int c4 = (v & 15) * 4;
        *reinterpret_cast<float4*>(&Ws[k][c4]) =
            *reinterpret_cast<const float4*>(&W2[(size_t)k * NCLS + c4]);
    }
    #pragma unroll
    for (int t = 0; t < 2; ++t) {
        int v = tid + t * 256;
        int r = v >> 5;
        int c4 = (v & 31) * 4;
        int gr = i0 + r; if (gr > N - 1) gr = N - 1;
        *reinterpret_cast<float4*>(&Ys[r][c4]) =
            *reinterpret_cast<const float4*>(&Y[(size_t)gr * NHID + c4]);
    }
    __syncthreads();
    const int c = tid & 63;
    const int rg = tid >> 6;
    float acc[4] = {0.f, 0.f, 0.f, 0.f};
    #pragma unroll 8
    for (int k = 0; k < NHID; ++k) {
        float w = Ws[k][c];
        #pragma unroll
        for (int j = 0; j < 4; ++j)
            acc[j] = fmaf(Ys[rg * 4 + j][k], w, acc[j]);
    }
    #pragma unroll
    for (int j = 0; j < 4; ++j) {
        int gr = i0 + rg * 4 + j;
        if (gr < N) H2s16[(size_t)gr * NCLS + c] = __float2half(acc[j] * dinv[gr]);
    }
}

// ---------------- AGG2 + softmax: two nodes per wave ----------------

__global__ __launch_bounds__(64) void agg2_kernel(const __half2* __restrict__ H2,
        const int* __restrict__ row_ptr, const int* __restrict__ col,
        const float* __restrict__ dinv, const float* __restrict__ b2,
        float* __restrict__ out, int N) {
    const int lane = threadIdx.x;
    const int node = blockIdx.x * 2 + (lane >> 5);
    const int c = lane & 31;             // col-pair 0..31
    if (node >= N) return;
    const int beg = row_ptr[node], end = row_ptr[node + 1];
    float2 f = __half22float2(H2[(size_t)node * 32 + c]);
    float ax = f.x, ay = f.y;
    int e = beg;
    for (; e + 8 <= end; e += 8) {
        float2 v[8];
        #pragma unroll
        for (int j = 0; j < 8; ++j) {
            int s = col[e + j];
            v[j] = __half22float2(H2[(size_t)s * 32 + c]);
        }
        #pragma unroll
        for (int j = 0; j < 8; ++j) { ax += v[j].x; ay += v[j].y; }
    }
    for (; e < end; ++e) {
        float2 v = __half22float2(H2[(size_t)col[e] * 32 + c]);
        ax += v.x; ay += v.y;
    }
    const float di = dinv[node];
    const float2 bb = reinterpret_cast<const float2*>(b2)[c];
    float vx = fmaf(ax, di, bb.x);
    float vy = fmaf(ay, di, bb.y);
    float m = fmaxf(vx, vy);
    #pragma unroll
    for (int d = 16; d >= 1; d >>= 1) m = fmaxf(m, __shfl_xor(m, d));
    float ex = __expf(vx - m), ey = __expf(vy - m);
    float sum = ex + ey;
    #pragma unroll
    for (int d = 16; d >= 1; d >>= 1) sum += __shfl_xor(sum, d);
    float2 o = {ex / sum, ey / sum};
    reinterpret_cast<float2*>(out)[(size_t)node * 32 + c] = o;
}

// ---------------- launch ----------------

extern "C" void kernel_launch(void* const* d_in, const int* in_sizes, int n_in,
                              void* d_out, int out_size, void* d_ws, size_t ws_size,
                              hipStream_t stream) {
    const float* x  = (const float*)d_in[0];
    const int*   ei = (const int*)d_in[1];
    const float* W1 = (const float*)d_in[2];
    const float* b1 = (const float*)d_in[3];
    const float* W2 = (const float*)d_in[4];
    const float* b2 = (const float*)d_in[5];
    const int N = in_sizes[0] / F_IN;
    const int E = in_sizes[1] / 2;
    const int* src = ei;
    const int* dst = ei + E;
    float* out = (float*)d_out;

    const int Npad  = (N + 63) & ~63;
    const int Nb256 = (N + 255) & ~255;           // cnt size (bucket-dense)
    const int Epad  = (E + 63) & ~63;
    int*    cnt     = (int*)d_ws;                 // Nb256
    int*    bcur    = cnt + Nb256;                // 256
    int*    row_ptr = bcur + 256;                 // Npad (>= N+1)
    float*  dinv    = (float*)(row_ptr + Npad);   // Npad
    int*    col     = (int*)(dinv + Npad);        // Epad
    int*    bsum    = col + Epad;                 // 64
    int*    boff    = bsum + 64;                  // 64
    __half* Hs16    = (__half*)(boff + 64);       // Npad*128 halfs (12.8MB)
    float*  Y       = (float*)(Hs16 + (size_t)Npad * NHID);  // Npad*128 f32 (25.6MB)
    __half* H2s16   = Hs16;                       // reuse (Hs dead after agg1)
    short*  Whp     = (short*)Y;                  // overlay Y start (128KB)
    short*  Wlp     = Whp + (size_t)F_IN * NHID;  // +128KB
    // bucket pair storage overlays Y at +512KB; dead before agg1 writes Y
    int2*   pairs   = (int2*)((char*)Y + 512 * 1024);

    const int nb = (N + 1023) / 1024;
    const int nbuck = (N + 255) >> BSHIFT;                  // 196
    const int cap = (((E / nbuck) * 3 / 2) + 63) & ~63;     // ~12288

    hipMemsetAsync(bcur, 0, 256 * sizeof(int), stream);
    bin_kernel<<<(E + CHUNK - 1) / CHUNK, 256, 0, stream>>>(src, dst, pairs, bcur, E, cap);
    count_b_kernel<<<nbuck, 256, 0, stream>>>(pairs, bcur, cnt, cap);
    scan1_kernel<<<nb, 256, 0, stream>>>(cnt, row_ptr, dinv, bsum, N);
    scan2_kernel<<<1, 64, 0, stream>>>(bsum, boff, row_ptr, nb, N);
    scan3_kernel<<<(N + 255) / 256, 256, 0, stream>>>(row_ptr, boff, N);
    fill_b_kernel<<<nbuck, 512, 0, stream>>>(pairs, bcur, row_ptr, col, cap);
    prepW_kernel<<<32, 256, 0, stream>>>(W1, Whp, Wlp);
    gemm1_mfma<<<(N + 63) / 64, 256, 0, stream>>>(x, Whp, Wlp, dinv, Hs16, N);
    agg1_kernel<<<N, 64, 0, stream>>>((const __half2*)Hs16, row_ptr, col, dinv, b1, Y);
    gemm2_kernel<<<(N + 15) / 16, 256, 0, stream>>>(Y, W2, dinv, H2s16, N);
    agg2_kernel<<<(N + 1) / 2, 64, 0, stream>>>((const __half2*)H2s16, row_ptr, col, dinv, b2, out, N);
}

// Round 8
// 203.712 us; speedup vs baseline: 1.1472x; 1.0880x over previous
//
#include <hip/hip_runtime.h>
#include <hip/hip_bf16.h>
#include <hip/hip_fp16.h>

// ---------------------------------------------------------------------------
// GCN 2-layer inference:
//   h1 = relu( D^-1/2 (A+I) D^-1/2 (x @ W1) + b1 )
//   out = softmax( D^-1/2 (A+I) D^-1/2 (h1 @ W2) + b2 )
//
// memset(bcur) -> bin -> count_b -> scan1/2/3 -> fill_b -> prepW ->
// gemm1_mfma (register-direct split-bf16 MFMA, 32 rows/wave, ping-pong
// B-frag pipeline) -> agg1 -> gemm2 -> agg2.
//
// Round-7 lesson: VGPR=56 showed the compiler serialized B loads (16 L2
// round-trips per K-step, MfmaUtil 9.6%). Now: 32 rows/wave (halves total
// B traffic to 400MB + doubles MFMA per load) and an explicit ping-pong
// register pipeline so B loads stay one slot ahead of their MFMAs; A raw
// loads issue a full K-step ahead.
// ---------------------------------------------------------------------------

#define F_IN 512
#define NHID 128
#define NCLS 64
#define BSHIFT 8           // 256 nodes per bucket
#define CHUNK 4096         // edges per bin block

typedef __attribute__((ext_vector_type(8))) short short8;
typedef __attribute__((ext_vector_type(4))) float f32x4;

__device__ __forceinline__ unsigned f2u(float f) { union { float f; unsigned u; } v; v.f = f; return v.u; }
__device__ __forceinline__ float u2f(unsigned u) { union { unsigned u; float f; } v; v.u = u; return v.f; }

// ---------------- binning: LDS counting-sort of 4096-edge chunks by bucket ----------------

__global__ __launch_bounds__(256) void bin_kernel(const int* __restrict__ src,
        const int* __restrict__ dst, int2* __restrict__ pairs,
        int* __restrict__ bcur, int E, int cap) {
    __shared__ int lcnt[256];
    __shared__ int lscan[256];
    __shared__ int gbase[256];
    __shared__ int wsum[4];
    __shared__ int2 stage[CHUNK];
    const int t = threadIdx.x;
    const int lane = t & 63, wid = t >> 6;
    const int e0 = blockIdx.x * CHUNK;
    const int n = min(CHUNK, E - e0);

    lcnt[t] = 0;
    __syncthreads();
    for (int i = t; i < n; i += 256)
        atomicAdd(&lcnt[dst[e0 + i] >> BSHIFT], 1);
    __syncthreads();
    const int v = lcnt[t];
    int s = v;
    #pragma unroll
    for (int d = 1; d < 64; d <<= 1) {
        int tt = __shfl_up(s, d);
        if (lane >= d) s += tt;
    }
    if (lane == 63) wsum[wid] = s;
    __syncthreads();
    int woff = 0;
    for (int w = 0; w < wid; ++w) woff += wsum[w];
    lscan[t] = woff + s - v;
    gbase[t] = v ? atomicAdd(&bcur[t], v) : 0;
    lcnt[t] = 0;
    __syncthreads();
    for (int i = t; i < n; i += 256) {
        int d = dst[e0 + i], sc = src[e0 + i];
        int b = d >> BSHIFT;
        int p = atomicAdd(&lcnt[b], 1);
        stage[lscan[b] + p] = make_int2(d, sc);
    }
    __syncthreads();
    for (int i = t; i < n; i += 256) {
        int2 pr = stage[i];
        int b = pr.x >> BSHIFT;
        int off = gbase[b] + (i - lscan[b]);
        if (off < cap) pairs[(size_t)b * cap + off] = pr;
    }
}

// ---------------- per-bucket degree count (LDS histogram, dense cnt write) ----------------

__global__ __launch_bounds__(256) void count_b_kernel(const int2* __restrict__ pairs,
        const int* __restrict__ bcur, int* __restrict__ cnt, int cap) {
    __shared__ int hist[256];
    const int b = blockIdx.x;
    const int t = threadIdx.x;
    hist[t] = 0;
    __syncthreads();
    const int n = min(bcur[b], cap);
    const int2* p = pairs + (size_t)b * cap;
    for (int i = t; i < n; i += 256)
        atomicAdd(&hist[p[i].x & 255], 1);
    __syncthreads();
    cnt[(b << BSHIFT) + t] = hist[t];
}

// ---------------- row_ptr scan ----------------

__global__ __launch_bounds__(256) void scan1_kernel(const int* __restrict__ cnt,
        int* __restrict__ row_ptr, float* __restrict__ dinv,
        int* __restrict__ bsum, int N) {
    __shared__ int wsum[4];
    const int tid = threadIdx.x;
    const int lane = tid & 63, wid = tid >> 6;
    const int base = blockIdx.x * 1024 + tid * 4;
    int4 v = {0, 0, 0, 0};
    if (base + 3 < N) {
        v = *reinterpret_cast<const int4*>(&cnt[base]);
    } else {
        if (base + 0 < N) v.x = cnt[base + 0];
        if (base + 1 < N) v.y = cnt[base + 1];
        if (base + 2 < N) v.z = cnt[base + 2];
        if (base + 3 < N) v.w = cnt[base + 3];
    }
    if (base + 0 < N) dinv[base + 0] = rsqrtf((float)v.x + 1.0f);
    if (base + 1 < N) dinv[base + 1] = rsqrtf((float)v.y + 1.0f);
    if (base + 2 < N) dinv[base + 2] = rsqrtf((float)v.z + 1.0f);
    if (base + 3 < N) dinv[base + 3] = rsqrtf((float)v.w + 1.0f);
    const int tsum = v.x + v.y + v.z + v.w;
    int s = tsum;
    #pragma unroll
    for (int d = 1; d < 64; d <<= 1) {
        int t = __shfl_up(s, d);
        if (lane >= d) s += t;
    }
    if (lane == 63) wsum[wid] = s;
    __syncthreads();
    int woff = 0;
    for (int w = 0; w < wid; ++w) woff += wsum[w];
    const int excl = woff + s - tsum;
    if (base + 0 < N) row_ptr[base + 0] = excl;
    if (base + 1 < N) row_ptr[base + 1] = excl + v.x;
    if (base + 2 < N) row_ptr[base + 2] = excl + v.x + v.y;
    if (base + 3 < N) row_ptr[base + 3] = excl + v.x + v.y + v.z;
    if (tid == 255) bsum[blockIdx.x] = excl + tsum;
}

__global__ __launch_bounds__(64) void scan2_kernel(const int* __restrict__ bsum,
        int* __restrict__ boff, int* __restrict__ row_ptr, int nb, int N) {
    const int lane = threadIdx.x;
    int v = (lane < nb) ? bsum[lane] : 0;
    int s = v;
    #pragma unroll
    for (int d = 1; d < 64; d <<= 1) {
        int t = __shfl_up(s, d);
        if (lane >= d) s += t;
    }
    if (lane < nb) boff[lane] = s - v;
    if (lane == 63) row_ptr[N] = s;
}

__global__ void scan3_kernel(int* __restrict__ row_ptr, const int* __restrict__ boff, int N) {
    int i = blockIdx.x * blockDim.x + threadIdx.x;
    if (i < N) row_ptr[i] += boff[i >> 10];
}

// ---------------- CSR placement: LDS cursor, bucket-local col writes ----------------

__global__ __launch_bounds__(512) void fill_b_kernel(const int2* __restrict__ pairs,
        const int* __restrict__ bcur, const int* __restrict__ row_ptr,
        int* __restrict__ col, int cap) {
    __shared__ int lcur[256];
    const int b = blockIdx.x;
    const int t = threadIdx.x;
    if (t < 256) lcur[t] = 0;
    __syncthreads();
    const int n = min(bcur[b], cap);
    const int2* p = pairs + (size_t)b * cap;
    for (int i = t; i < n; i += 512) {
        int2 pr = p[i];
        int pos = row_ptr[pr.x] + atomicAdd(&lcur[pr.x & 255], 1);
        col[pos] = pr.y;
    }
}

// ---------------- prepW: W1 -> fragment-packed hi/lo bf16 ----------------
// Fragment f = ks*8 + nt. Lane l of frag f: cols nt*16+(l&15),
// k = ks*32+(l>>4)*8 .. +8. Stored at [f*512 + l*8] shorts.

__global__ __launch_bounds__(256) void prepW_kernel(const float* __restrict__ W1,
        short* __restrict__ Whp, short* __restrict__ Wlp) {
    const int g = blockIdx.x * 256 + threadIdx.x;  // 0..8191
    const int f = g >> 6;
    const int lane = g & 63;
    const int ks = f >> 3, nt = f & 7;
    const int colg = nt * 16 + (lane & 15);
    const int k0 = ks * 32 + (lane >> 4) * 8;
    short8 vh, vl;
    #pragma unroll
    for (int j = 0; j < 8; ++j) {
        float w = W1[(size_t)(k0 + j) * NHID + colg];
        unsigned u = f2u(w);
        vh[j] = (short)(u >> 16);
        float hif = u2f(u & 0xffff0000u);
        vl[j] = (short)(f2u(w - hif) >> 16);
    }
    *reinterpret_cast<short8*>(Whp + ((size_t)f << 9) + (lane << 3)) = vh;
    *reinterpret_cast<short8*>(Wlp + ((size_t)f << 9) + (lane << 3)) = vl;
}

// ---------------- GEMM1: 32 rows/wave, ping-pong B pipeline ----------------

__device__ __forceinline__ void cvt8(const float4& u0, const float4& u1,
                                     short8& h, short8& l) {
    float av[8] = {u0.x, u0.y, u0.z, u0.w, u1.x, u1.y, u1.z, u1.w};
    #pragma unroll
    for (int j = 0; j < 8; ++j) {
        unsigned u = f2u(av[j]);
        h[j] = (short)(u >> 16);
        float hif = u2f(u & 0xffff0000u);
        l[j] = (short)(f2u(av[j] - hif) >> 16);
    }
}

#define LOADG(H0, L0, H1, L1, ks, g) { \
    const short* _p = Whp + (((size_t)((ks) * 8 + 2 * (g))) << 9) + (lane << 3); \
    const short* _q = Wlp + (((size_t)((ks) * 8 + 2 * (g))) << 9) + (lane << 3); \
    H0 = *reinterpret_cast<const short8*>(_p); \
    L0 = *reinterpret_cast<const short8*>(_q); \
    H1 = *reinterpret_cast<const short8*>(_p + 512); \
    L1 = *reinterpret_cast<const short8*>(_q + 512); }

#define MFMAG(H0, L0, H1, L1, g) { \
    acc[0][2*(g)]   = __builtin_amdgcn_mfma_f32_16x16x32_bf16(ah0, H0, acc[0][2*(g)], 0, 0, 0); \
    acc[0][2*(g)]   = __builtin_amdgcn_mfma_f32_16x16x32_bf16(ah0, L0, acc[0][2*(g)], 0, 0, 0); \
    acc[0][2*(g)]   = __builtin_amdgcn_mfma_f32_16x16x32_bf16(al0, H0, acc[0][2*(g)], 0, 0, 0); \
    acc[0][2*(g)+1] = __builtin_amdgcn_mfma_f32_16x16x32_bf16(ah0, H1, acc[0][2*(g)+1], 0, 0, 0); \
    acc[0][2*(g)+1] = __builtin_amdgcn_mfma_f32_16x16x32_bf16(ah0, L1, acc[0][2*(g)+1], 0, 0, 0); \
    acc[0][2*(g)+1] = __builtin_amdgcn_mfma_f32_16x16x32_bf16(al0, H1, acc[0][2*(g)+1], 0, 0, 0); \
    acc[1][2*(g)]   = __builtin_amdgcn_mfma_f32_16x16x32_bf16(ah1, H0, acc[1][2*(g)], 0, 0, 0); \
    acc[1][2*(g)]   = __builtin_amdgcn_mfma_f32_16x16x32_bf16(ah1, L0, acc[1][2*(g)], 0, 0, 0); \
    acc[1][2*(g)]   = __builtin_amdgcn_mfma_f32_16x16x32_bf16(al1, H0, acc[1][2*(g)], 0, 0, 0); \
    acc[1][2*(g)+1] = __builtin_amdgcn_mfma_f32_16x16x32_bf16(ah1, H1, acc[1][2*(g)+1], 0, 0, 0); \
    acc[1][2*(g)+1] = __builtin_amdgcn_mfma_f32_16x16x32_bf16(ah1, L1, acc[1][2*(g)+1], 0, 0, 0); \
    acc[1][2*(g)+1] = __builtin_amdgcn_mfma_f32_16x16x32_bf16(al1, H1, acc[1][2*(g)+1], 0, 0, 0); }

__global__ __launch_bounds__(256, 2) void gemm1_mfma(
        const float* __restrict__ X, const short* __restrict__ Whp,
        const short* __restrict__ Wlp, const float* __restrict__ dinv,
        __half* __restrict__ Hs16, int M) {
    const int tid = threadIdx.x;
    const int lane = tid & 63;
    const int wid = tid >> 6;
    const int l15 = lane & 15;
    const int kc = lane >> 4;
    const int rbase = blockIdx.x * 128 + wid * 32;

    int ar0 = rbase + l15;      if (ar0 > M - 1) ar0 = M - 1;
    int ar1 = rbase + 16 + l15; if (ar1 > M - 1) ar1 = M - 1;
    const float* xp0 = X + (size_t)ar0 * F_IN + kc * 8;
    const float* xp1 = X + (size_t)ar1 * F_IN + kc * 8;

    f32x4 acc[2][8];
    #pragma unroll
    for (int i = 0; i < 2; ++i)
        #pragma unroll
        for (int j = 0; j < 8; ++j)
            acc[i][j] = (f32x4){0.f, 0.f, 0.f, 0.f};

    short8 ah0, al0, ah1, al1;
    {
        float4 a00 = *reinterpret_cast<const float4*>(xp0);
        float4 a01 = *reinterpret_cast<const float4*>(xp0 + 4);
        float4 a10 = *reinterpret_cast<const float4*>(xp1);
        float4 a11 = *reinterpret_cast<const float4*>(xp1 + 4);
        cvt8(a00, a01, ah0, al0);
        cvt8(a10, a11, ah1, al1);
    }
    short8 p0h0, p0l0, p0h1, p0l1;   // ping
    short8 p1h0, p1l0, p1h1, p1l1;   // pong
    LOADG(p0h0, p0l0, p0h1, p0l1, 0, 0);

    for (int ks = 0; ks < 16; ++ks) {
        const bool last = (ks == 15);
        float4 n00, n01, n10, n11;
        if (!last) {
            n00 = *reinterpret_cast<const float4*>(xp0 + (ks + 1) * 32);
            n01 = *reinterpret_cast<const float4*>(xp0 + (ks + 1) * 32 + 4);
            n10 = *reinterpret_cast<const float4*>(xp1 + (ks + 1) * 32);
            n11 = *reinterpret_cast<const float4*>(xp1 + (ks + 1) * 32 + 4);
        }
        LOADG(p1h0, p1l0, p1h1, p1l1, ks, 1);
        MFMAG(p0h0, p0l0, p0h1, p0l1, 0);
        LOADG(p0h0, p0l0, p0h1, p0l1, ks, 2);
        MFMAG(p1h0, p1l0, p1h1, p1l1, 1);
        LOADG(p1h0, p1l0, p1h1, p1l1, ks, 3);
        MFMAG(p0h0, p0l0, p0h1, p0l1, 2);
        if (!last) LOADG(p0h0, p0l0, p0h1, p0l1, ks + 1, 0);
        MFMAG(p1h0, p1l0, p1h1, p1l1, 3);
        if (!last) {
            cvt8(n00, n01, ah0, al0);
            cvt8(n10, n11, ah1, al1);
        }
    }

    #pragma unroll
    for (int rr = 0; rr < 2; ++rr) {
        #pragma unroll
        for (int r = 0; r < 4; ++r) {
            const int orow = rbase + rr * 16 + kc * 4 + r;
            if (orow < M) {
                const float di = dinv[orow];
                #pragma unroll
                for (int nt = 0; nt < 8; ++nt) {
                    Hs16[(size_t)orow * NHID + nt * 16 + l15] =
                        __float2half(acc[rr][nt][r] * di);
                }
            }
        }
    }
}

// ---------------- AGG1: Y = relu(dinv[i]*(Hs[i] + sum Hs[src]) + b1) ----------------

__global__ __launch_bounds__(64) void agg1_kernel(const __half2* __restrict__ Hs,
        const int* __restrict__ row_ptr, const int* __restrict__ col,
        const float* __restrict__ dinv, const float* __restrict__ b1,
        float* __restrict__ Y) {
    const int i = blockIdx.x;
    const int c = threadIdx.x;           // col-pair 0..63
    const int beg = row_ptr[i], end = row_ptr[i + 1];
    float2 f = __half22float2(Hs[(size_t)i * 64 + c]);
    float ax = f.x, ay = f.y;
    int e = beg;
    for (; e + 8 <= end; e += 8) {
        float2 v[8];
        #pragma unroll
        for (int j = 0; j < 8; ++j) {
            int s = col[e + j];
            v[j] = __half22float2(Hs[(size_t)s * 64 + c]);
        }
        #pragma unroll
        for (int j = 0; j < 8; ++j) { ax += v[j].x; ay += v[j].y; }
    }
    for (; e < end; ++e) {
        float2 v = __half22float2(Hs[(size_t)col[e] * 64 + c]);
        ax += v.x; ay += v.y;
    }
    const float di = dinv[i];
    const float2 bb = reinterpret_cast<const float2*>(b1)[c];
    float2 o;
    o.x = fmaxf(fmaf(ax, di, bb.x), 0.0f);
    o.y = fmaxf(fmaf(ay, di, bb.y), 0.0f);
    *reinterpret_cast<float2*>(&Y[(size_t)i * NHID + 2 * c]) = o;
}

// ---------------- GEMM2: H2s16 = fp16((Y @ W2) * dinv[row])  [N,64] ----------------

__global__ __launch_bounds__(256) void gemm2_kernel(const float* __restrict__ Y,
        const float* __restrict__ W2, const float* __restrict__ dinv,
        __half* __restrict__ H2s16, int N) {
    __shared__ float Ws[NHID][NCLS];
    __shared__ float Ys[16][NHID];
    const int tid = threadIdx.x;
    const int i0 = blockIdx.x * 16;
    #pragma unroll
    for (int t = 0; t < 8; ++t) {
        int v = tid + t * 256;
        int k = v >> 4;
        int c4 = (v & 15) * 4;
        *reinterpret_cast<float4*>(&Ws[k][c4]) =
            *reinterpret_cast<const float4*>(&W2[(size_t)k * NCLS + c4]);
    }
    #pragma unroll
    for (int t = 0; t < 2; ++t) {
        int v = tid + t * 256;
        int r = v >> 5;
        int c4 = (v & 31) * 4;
        int gr = i0 + r; if (gr > N - 1) gr = N - 1;
        *reinterpret_cast<float4*>(&Ys[r][c4]) =
            *reinterpret_cast<const float4*>(&Y[(size_t)gr * NHID + c4]);
    }
    __syncthreads();
    const int c = tid & 63;
    const int rg = tid >> 6;
    float acc[4] = {0.f, 0.f, 0.f, 0.f};
    #pragma unroll 8
    for (int k = 0; k < NHID; ++k) {
        float w = Ws[k][c];
        #pragma unroll
        for (int j = 0; j < 4; ++j)
            acc[j] = fmaf(Ys[rg * 4 + j][k], w, acc[j]);
    }
    #pragma unroll
    for (int j = 0; j < 4; ++j) {
        int gr = i0 + rg * 4 + j;
        if (gr < N) H2s16[(size_t)gr * NCLS + c] = __float2half(acc[j] * dinv[gr]);
    }
}

// ---------------- AGG2 + softmax: two nodes per wave ----------------

__global__ __launch_bounds__(64) void agg2_kernel(const __half2* __restrict__ H2,
        const int* __restrict__ row_ptr, const int* __restrict__ col,
        const float* __restrict__ dinv, const float* __restrict__ b2,
        float* __restrict__ out, int N) {
    const int lane = threadIdx.x;
    const int node = blockIdx.x * 2 + (lane >> 5);
    const int c = lane & 31;             // col-pair 0..31
    if (node >= N) return;
    const int beg = row_ptr[node], end = row_ptr[node + 1];
    float2 f = __half22float2(H2[(size_t)node * 32 + c]);
    float ax = f.x, ay = f.y;
    int e = beg;
    for (; e + 8 <= end; e += 8) {
        float2 v[8];
        #pragma unroll
        for (int j = 0; j < 8; ++j) {
            int s = col[e + j];
            v[j] = __half22float2(H2[(size_t)s * 32 + c]);
        }
        #pragma unroll
        for (int j = 0; j < 8; ++j) { ax += v[j].x; ay += v[j].y; }
    }
    for (; e < end; ++e) {
        float2 v = __half22float2(H2[(size_t)col[e] * 32 + c]);
        ax += v.x; ay += v.y;
    }
    const float di = dinv[node];
    const float2 bb = reinterpret_cast<const float2*>(b2)[c];
    float vx = fmaf(ax, di, bb.x);
    float vy = fmaf(ay, di, bb.y);
    float m = fmaxf(vx, vy);
    #pragma unroll
    for (int d = 16; d >= 1; d >>= 1) m = fmaxf(m, __shfl_xor(m, d));
    float ex = __expf(vx - m), ey = __expf(vy - m);
    float sum = ex + ey;
    #pragma unroll
    for (int d = 16; d >= 1; d >>= 1) sum += __shfl_xor(sum, d);
    float2 o = {ex / sum, ey / sum};
    reinterpret_cast<float2*>(out)[(size_t)node * 32 + c] = o;
}

// ---------------- launch ----------------

extern "C" void kernel_launch(void* const* d_in, const int* in_sizes, int n_in,
                              void* d_out, int out_size, void* d_ws, size_t ws_size,
                              hipStream_t stream) {
    const float* x  = (const float*)d_in[0];
    const int*   ei = (const int*)d_in[1];
    const float* W1 = (const float*)d_in[2];
    const float* b1 = (const float*)d_in[3];
    const float* W2 = (const float*)d_in[4];
    const float* b2 = (const float*)d_in[5];
    const int N = in_sizes[0] / F_IN;
    const int E = in_sizes[1] / 2;
    const int* src = ei;
    const int* dst = ei + E;
    float* out = (float*)d_out;

    const int Npad  = (N + 63) & ~63;
    const int Nb256 = (N + 255) & ~255;           // cnt size (bucket-dense)
    const int Epad  = (E + 63) & ~63;
    int*    cnt     = (int*)d_ws;                 // Nb256
    int*    bcur    = cnt + Nb256;                // 256
    int*    row_ptr = bcur + 256;                 // Npad (>= N+1)
    float*  dinv    = (float*)(row_ptr + Npad);   // Npad
    int*    col     = (int*)(dinv + Npad);        // Epad
    int*    bsum    = col + Epad;                 // 64
    int*    boff    = bsum + 64;                  // 64
    __half* Hs16    = (__half*)(boff + 64);       // Npad*128 halfs (12.8MB)
    float*  Y       = (float*)(Hs16 + (size_t)Npad * NHID);  // Npad*128 f32 (25.6MB)
    __half* H2s16   = Hs16;                       // reuse (Hs dead after agg1)
    short*  Whp     = (short*)Y;                  // overlay Y start (128KB)
    short*  Wlp     = Whp + (size_t)F_IN * NHID;  // +128KB
    // bucket pair storage overlays Y at +512KB; dead before agg1 writes Y
    int2*   pairs   = (int2*)((char*)Y + 512 * 1024);

    const int nb = (N + 1023) / 1024;
    const int nbuck = (N + 255) >> BSHIFT;                  // 196
    const int cap = (((E / nbuck) * 3 / 2) + 63) & ~63;     // ~12288

    hipMemsetAsync(bcur, 0, 256 * sizeof(int), stream);
    bin_kernel<<<(E + CHUNK - 1) / CHUNK, 256, 0, stream>>>(src, dst, pairs, bcur, E, cap);
    count_b_kernel<<<nbuck, 256, 0, stream>>>(pairs, bcur, cnt, cap);
    scan1_kernel<<<nb, 256, 0, stream>>>(cnt, row_ptr, dinv, bsum, N);
    scan2_kernel<<<1, 64, 0, stream>>>(bsum, boff, row_ptr, nb, N);
    scan3_kernel<<<(N + 255) / 256, 256, 0, stream>>>(row_ptr, boff, N);
    fill_b_kernel<<<nbuck, 512, 0, stream>>>(pairs, bcur, row_ptr, col, cap);
    prepW_kernel<<<32, 256, 0, stream>>>(W1, Whp, Wlp);
    gemm1_mfma<<<(N + 127) / 128, 256, 0, stream>>>(x, Whp, Wlp, dinv, Hs16, N);
    agg1_kernel<<<N, 64, 0, stream>>>((const __half2*)Hs16, row_ptr, col, dinv, b1, Y);
    gemm2_kernel<<<(N + 15) / 16, 256, 0, stream>>>(Y, W2, dinv, H2s16, N);
    agg2_kernel<<<(N + 1) / 2, 64, 0, stream>>>((const __half2*)H2s16, row_ptr, col, dinv, b2, out, N);
}